// Round 8
// baseline (1896.881 us; speedup 1.0000x reference)
//
#include <hip/hip_runtime.h>
#include <hip/hip_bf16.h>
#include <cstdint>

#define DEV static __device__ __forceinline__

typedef __attribute__((ext_vector_type(8))) short bf16x8;
typedef __attribute__((ext_vector_type(4))) float f32x4;

// ---------- bf16 helpers (bit-level) ----------
DEV unsigned short f2bf(float f) {
  union { float f; unsigned u; } c; c.f = f;
  unsigned u = c.u;
  return (unsigned short)((u + 0x7fffu + ((u >> 16) & 1u)) >> 16);  // RNE
}
DEV float bf2f(unsigned short h) {
  union { unsigned u; float f; } c; c.u = ((unsigned)h) << 16; return c.f;
}
// fast round-half-up bf16 pair pack: lo16 = bf(a), hi16 = bf(b), 3 VALU ops
DEV unsigned pack_bf16(float a, float b) {
  union { float f; unsigned u; } ca, cb; ca.f = a; cb.f = b;
  return __builtin_amdgcn_perm(cb.u + 0x8000u, ca.u + 0x8000u, 0x07060302u);
}

// async global->LDS, 16B per lane; LDS dest is wave-uniform base + lane*16
#define ASYNC_COPY16(gsrc, ldst)                                                      \
  __builtin_amdgcn_global_load_lds(                                                   \
      (const __attribute__((address_space(1))) void*)(unsigned long long)(gsrc),      \
      (__attribute__((address_space(3))) void*)(unsigned int)(unsigned long long)(ldst), \
      16, 0, 0)

// =====================================================================
// fp32 -> bf16 weight conversion, 4 elems/thread
// =====================================================================
__global__ void cvt4_kernel(const float* __restrict__ s, unsigned short* __restrict__ d) {
  size_t i = ((size_t)blockIdx.x * 256 + threadIdx.x) * 4;
  float4 v = *(const float4*)(s + i);
  d[i + 0] = f2bf(v.x);
  d[i + 1] = f2bf(v.y);
  d[i + 2] = f2bf(v.z);
  d[i + 3] = f2bf(v.w);
}

// =====================================================================
// embedding + positional encoding: x[bs,d] (fp32 master + bf16 copy)
// =====================================================================
__global__ void embed_kernel(const float* __restrict__ src,    // [B*S,16]
                             const float* __restrict__ emb_w,  // [512,16]
                             const float* __restrict__ emb_b,  // [512]
                             float* __restrict__ x,
                             unsigned short* __restrict__ xb) {
  const int bs = blockIdx.x;        // 0..16383
  const int d = threadIdx.x;        // 0..511
  const int s = bs & 255;
  __shared__ float sv[16];
  if (d < 16) sv[d] = src[(size_t)bs * 16 + d];
  __syncthreads();
  const float* wr = emb_w + (size_t)d * 16;
  float acc = emb_b[d];
#pragma unroll
  for (int v = 0; v < 16; v++) acc += sv[v] * wr[v];
  const float den = __expf(-(float)(d & ~1) * (9.2103403719761836f / 512.f));
  const float arg = (float)s * den;
  acc += (d & 1) ? __cosf(arg) : __sinf(arg);
  x[(size_t)bs * 512 + d] = acc;
  xb[(size_t)bs * 512 + d] = f2bf(acc);
}

// =====================================================================
// bf16 MFMA GEMM, NT: C[m,n] = sum_k A[m,k]*B[n,k] + bias[n]
// BM=128, BN=128, BK=64, 256 thr, waves 2x2, acc 4x4, 3 blocks/CU.
// Grid: x = m-tiles (XCD = id%8 = m%8 -> A-tile L2 locality), y = n-blocks.
// LDS XOR swizzle (row stride 128B): chunk slot s of row r holds global
// chunk s^(r&7); readers use (kh*4+quad)^(r16&7) -> conflict-free b128.
// Operands swapped (A_op=weights) so lane's 4 acc regs = 4 consecutive n.
// =====================================================================
template <int RELU>
__global__ __launch_bounds__(256, 3) void gemm_nt(
    const unsigned short* __restrict__ A,   // [M,K] bf16 activations
    const unsigned short* __restrict__ B,   // [N,K] bf16 weights
    const float* __restrict__ bias,         // [N]
    unsigned short* __restrict__ Cb,        // [M,N] bf16 out
    int M, int N, int K) {
  __shared__ unsigned short As[128 * 64];
  __shared__ unsigned short Bs[128 * 64];
  const int tid = threadIdx.x;
  const int lane = tid & 63;
  const int w = tid >> 6;
  const int m0 = blockIdx.x * 128;
  const int n0 = blockIdx.y * 128;

  const int srow = lane >> 3;                  // 0..7
  const int scol = (((lane & 7) ^ srow)) * 8;  // swizzled chunk
  const unsigned short* gA0 = A + (size_t)(m0 + w * 32 + srow) * K + scol;
  unsigned short* lA0 = As + (w * 32) * 64;
  const unsigned short* gB0 = B + (size_t)(n0 + w * 32 + srow) * K + scol;
  unsigned short* lB0 = Bs + (w * 32) * 64;

  const int wm = (w >> 1) * 64;
  const int wn = (w & 1) * 64;
  const int r16 = lane & 15;
  const int quad = lane >> 4;
  const int rsw = r16 & 7;

  f32x4 acc[4][4] = {};  // acc[i][j]: D[n=quad*4+r][m=r16]

  for (int k0 = 0; k0 < K; k0 += 64) {
#pragma unroll
    for (int i = 0; i < 4; i++) {
      ASYNC_COPY16(gA0 + (size_t)(i * 8) * K + k0, lA0 + i * 512);
      ASYNC_COPY16(gB0 + (size_t)(i * 8) * K + k0, lB0 + i * 512);
    }
    __syncthreads();
#pragma unroll
    for (int kh = 0; kh < 2; kh++) {
      const int ko = ((kh * 4 + quad) ^ rsw) * 8;
      bf16x8 xa[4], wb[4];
#pragma unroll
      for (int i = 0; i < 4; i++)
        xa[i] = *(const bf16x8*)(As + (wm + i * 16 + r16) * 64 + ko);
#pragma unroll
      for (int j = 0; j < 4; j++)
        wb[j] = *(const bf16x8*)(Bs + (wn + j * 16 + r16) * 64 + ko);
#pragma unroll
      for (int i = 0; i < 4; i++)
#pragma unroll
        for (int j = 0; j < 4; j++)
          acc[i][j] = __builtin_amdgcn_mfma_f32_16x16x32_bf16(wb[j], xa[i], acc[i][j], 0, 0, 0);
    }
    __syncthreads();
  }

  const int mb = m0 + wm + r16;
  const int nb = n0 + wn + quad * 4;
#pragma unroll
  for (int j = 0; j < 4; j++) {
    const int n = nb + j * 16;
    const float4 bv = *(const float4*)(bias + n);
#pragma unroll
    for (int i = 0; i < 4; i++) {
      const size_t off = (size_t)(mb + i * 16) * N + n;
      float4 v;
      v.x = acc[i][j][0] + bv.x;
      v.y = acc[i][j][1] + bv.y;
      v.z = acc[i][j][2] + bv.z;
      v.w = acc[i][j][3] + bv.w;
      if (RELU) {
        v.x = fmaxf(v.x, 0.f); v.y = fmaxf(v.y, 0.f);
        v.z = fmaxf(v.z, 0.f); v.w = fmaxf(v.w, 0.f);
      }
      uint2 u;
      u.x = pack_bf16(v.x, v.y);
      u.y = pack_bf16(v.z, v.w);
      *(uint2*)(Cb + off) = u;
    }
  }
}

// =====================================================================
// Fused GEMM + residual + LayerNorm for N=512 projections:
// x_out = LN(A.B^T + bias + x_in) ; writes x fp32 + xb bf16.
// BM=32 (grid 512 -> XCD=m%8, A read once), BN=512 (full row per block),
// BK=32. Wave w owns n in [w*128,w*128+128), all 32 rows; acc 2x8.
// LN: lane partials -> quad shfl -> 4-wave LDS reduce -> normalize.
// BK=32 swizzle key (r>>1)&3 (row stride 64B: bank period 2 rows, so
// r&3 key would leave 4-way conflicts; this gives 2-way = free).
// =====================================================================
__global__ __launch_bounds__(256, 2) void gemm_ln(
    const unsigned short* __restrict__ A,  // [16384,K] bf16
    const unsigned short* __restrict__ B,  // [512,K] bf16 weights
    const float* __restrict__ bias,        // [512]
    const float* __restrict__ g,           // [512] LN gamma
    const float* __restrict__ bb,          // [512] LN beta
    float* __restrict__ x,                 // [16384,512] fp32 in(res)/out
    unsigned short* __restrict__ xb,       // [16384,512] bf16 out
    int K) {
  __shared__ unsigned short As[32 * 32];    // 2KB
  __shared__ unsigned short Bs[512 * 32];   // 32KB
  __shared__ float redS[4][2][16];
  __shared__ float redQ[4][2][16];
  const int tid = threadIdx.x;
  const int lane = tid & 63;
  const int w = tid >> 6;
  const int r16 = lane & 15;
  const int quad = lane >> 4;
  const int m0 = blockIdx.x * 32;

  const int srow = lane >> 2;                           // 0..15
  const int scol = ((lane & 3) ^ ((srow >> 1) & 3)) * 8;
  const unsigned short* gB0 = B + (size_t)(w * 128 + srow) * K + scol;
  unsigned short* lB0 = Bs + (w * 128) * 32;
  const unsigned short* gA0 = A + (size_t)(m0 + (w & 1) * 16 + srow) * K + scol;
  unsigned short* lA0 = As + ((w & 1) * 16) * 32;

  const int ko = (quad ^ ((r16 >> 1) & 3)) * 8;

  f32x4 acc[2][8] = {};  // acc[i][j]: D[n=w*128+j*16+quad*4+r][m=m0+i*16+r16]

  for (int k0 = 0; k0 < K; k0 += 32) {
    if (w < 2) ASYNC_COPY16(gA0 + k0, lA0);
#pragma unroll
    for (int i = 0; i < 8; i++)
      ASYNC_COPY16(gB0 + (size_t)(i * 16) * K + k0, lB0 + i * 512);
    __syncthreads();
    bf16x8 xa[2], wv[8];
#pragma unroll
    for (int i = 0; i < 2; i++)
      xa[i] = *(const bf16x8*)(As + (i * 16 + r16) * 32 + ko);
#pragma unroll
    for (int j = 0; j < 8; j++)
      wv[j] = *(const bf16x8*)(Bs + (w * 128 + j * 16 + r16) * 32 + ko);
#pragma unroll
    for (int i = 0; i < 2; i++)
#pragma unroll
      for (int j = 0; j < 8; j++)
        acc[i][j] = __builtin_amdgcn_mfma_f32_16x16x32_bf16(wv[j], xa[i], acc[i][j], 0, 0, 0);
    __syncthreads();
  }

  // phase 1: z = acc + bias + res; per-row partial sums
#pragma unroll
  for (int i = 0; i < 2; i++) {
    const int m = m0 + i * 16 + r16;
    float s = 0.f, q = 0.f;
#pragma unroll
    for (int j = 0; j < 8; j++) {
      const int n = w * 128 + j * 16 + quad * 4;
      const float4 bv = *(const float4*)(bias + n);
      const float4 rr = *(const float4*)(x + (size_t)m * 512 + n);
      acc[i][j][0] += bv.x + rr.x;
      acc[i][j][1] += bv.y + rr.y;
      acc[i][j][2] += bv.z + rr.z;
      acc[i][j][3] += bv.w + rr.w;
      s += acc[i][j][0] + acc[i][j][1] + acc[i][j][2] + acc[i][j][3];
      q += acc[i][j][0] * acc[i][j][0] + acc[i][j][1] * acc[i][j][1] +
           acc[i][j][2] * acc[i][j][2] + acc[i][j][3] * acc[i][j][3];
    }
    s += __shfl_xor(s, 16); s += __shfl_xor(s, 32);
    q += __shfl_xor(q, 16); q += __shfl_xor(q, 32);
    if (quad == 0) { redS[w][i][r16] = s; redQ[w][i][r16] = q; }
  }
  __syncthreads();
  // phase 2: LN normalize + store
#pragma unroll
  for (int i = 0; i < 2; i++) {
    const int m = m0 + i * 16 + r16;
    const float st = redS[0][i][r16] + redS[1][i][r16] + redS[2][i][r16] + redS[3][i][r16];
    const float qt = redQ[0][i][r16] + redQ[1][i][r16] + redQ[2][i][r16] + redQ[3][i][r16];
    const float mu = st * (1.f / 512.f);
    const float rs = rsqrtf(qt * (1.f / 512.f) - mu * mu + 1e-5f);
#pragma unroll
    for (int j = 0; j < 8; j++) {
      const int n = w * 128 + j * 16 + quad * 4;
      const float4 gv = *(const float4*)(g + n);
      const float4 b2 = *(const float4*)(bb + n);
      float4 v;
      v.x = (acc[i][j][0] - mu) * rs * gv.x + b2.x;
      v.y = (acc[i][j][1] - mu) * rs * gv.y + b2.y;
      v.z = (acc[i][j][2] - mu) * rs * gv.z + b2.z;
      v.w = (acc[i][j][3] - mu) * rs * gv.w + b2.w;
      *(float4*)(x + (size_t)m * 512 + n) = v;
      uint2 u;
      u.x = pack_bf16(v.x, v.y);
      u.y = pack_bf16(v.z, v.w);
      *(uint2*)(xb + (size_t)m * 512 + n) = u;
    }
  }
}

// =====================================================================
// Fused attention: one block per (b,h). V^T staged once (33.8KB);
// loop over 8 q-tiles of 32: S^T scores (wave = k-quarter, A=K, B=Q from
// global), two-phase LDS softmax (max then sum), P packed to LDS (16.9KB,
// stride 264 -> 2-way reads), PV as O^T = Vt.P, uint2 packed O stores.
// =====================================================================
__global__ __launch_bounds__(256, 2) void attn_fused(
    const unsigned short* __restrict__ qkv,  // [B*S,1536] bf16 q|k|v
    unsigned short* __restrict__ O) {        // [B*S,512] bf16
  __shared__ unsigned short Vt[64 * 264];  // V^T[d][k], stride 264
  __shared__ unsigned short Pl[32 * 264];  // P[q][k],  stride 264
  __shared__ float redM[4][32];
  __shared__ float redS[4][32];
  const int tid = threadIdx.x;
  const int lane = tid & 63;
  const int w = tid >> 6;
  const int r16 = lane & 15;
  const int quad = lane >> 4;
  const int h = blockIdx.x & 7;
  const int b = blockIdx.x >> 3;

  // stage V^T (verified round-2 pattern)
  {
    const int kp = w * 32 + (lane & 31);
    const int dhalf = lane >> 5;
    const unsigned short* vbase =
        qkv + (size_t)(b * 256 + 2 * kp) * 1536 + 1024 + h * 64;
    unsigned* dst = (unsigned*)Vt;
#pragma unroll
    for (int t = 0; t < 4; t++) {
      const int dc = dhalf + 2 * t;  // d-chunk 0..7
      const uint4 a = *(const uint4*)(vbase + dc * 8);
      const uint4 bb = *(const uint4*)(vbase + 1536 + dc * 8);
      const unsigned* ap = (const unsigned*)&a;
      const unsigned* bp = (const unsigned*)&bb;
#pragma unroll
      for (int i = 0; i < 4; i++) {
        const unsigned lo = ap[i], hi = bp[i];
        dst[(dc * 8 + 2 * i) * 132 + kp] = (lo & 0xffffu) | (hi << 16);
        dst[(dc * 8 + 2 * i + 1) * 132 + kp] = (lo >> 16) | (hi & 0xffff0000u);
      }
    }
  }
  __syncthreads();

  const unsigned short* krow =
      qkv + (size_t)(b * 256 + r16) * 1536 + 512 + h * 64 + quad * 8;
  const unsigned short* qrow =
      qkv + (size_t)(b * 256 + r16) * 1536 + h * 64 + quad * 8;

  for (int qt = 0; qt < 8; qt++) {
    const int q0 = qt * 32;
    f32x4 acc[4][2] = {};  // acc[mt][nt]: S^T[k=w*64+mt*16+quad*4+r][q=q0+nt*16+r16]
    bf16x8 bQ0[2], bQ1[2];
#pragma unroll
    for (int nt = 0; nt < 2; nt++) {
      const unsigned short* qp = qrow + (size_t)(q0 + nt * 16) * 1536;
      bQ0[nt] = *(const bf16x8*)(qp);
      bQ1[nt] = *(const bf16x8*)(qp + 32);
    }
#pragma unroll
    for (int mt = 0; mt < 4; mt++) {
      const unsigned short* kp = krow + (size_t)(w * 64 + mt * 16) * 1536;
      const bf16x8 aK0 = *(const bf16x8*)(kp);
      const bf16x8 aK1 = *(const bf16x8*)(kp + 32);
#pragma unroll
      for (int nt = 0; nt < 2; nt++) {
        acc[mt][nt] = __builtin_amdgcn_mfma_f32_16x16x32_bf16(aK0, bQ0[nt], acc[mt][nt], 0, 0, 0);
        acc[mt][nt] = __builtin_amdgcn_mfma_f32_16x16x32_bf16(aK1, bQ1[nt], acc[mt][nt], 0, 0, 0);
      }
    }
#pragma unroll
    for (int nt = 0; nt < 2; nt++) {
      float m = acc[0][nt][0];
#pragma unroll
      for (int mt = 0; mt < 4; mt++)
#pragma unroll
        for (int r = 0; r < 4; r++) m = fmaxf(m, acc[mt][nt][r]);
      m = fmaxf(m, __shfl_xor(m, 16));
      m = fmaxf(m, __shfl_xor(m, 32));
      if (quad == 0) redM[w][nt * 16 + r16] = m;
    }
    __syncthreads();
    float mg[2], sw[2];
#pragma unroll
    for (int nt = 0; nt < 2; nt++) {
      const int q = nt * 16 + r16;
      mg[nt] = fmaxf(fmaxf(redM[0][q], redM[1][q]), fmaxf(redM[2][q], redM[3][q]));
      sw[nt] = 0.f;
    }
#pragma unroll
    for (int mt = 0; mt < 4; mt++)
#pragma unroll
      for (int nt = 0; nt < 2; nt++)
#pragma unroll
        for (int r = 0; r < 4; r++) {
          acc[mt][nt][r] = __expf((acc[mt][nt][r] - mg[nt]) * 0.125f);
          sw[nt] += acc[mt][nt][r];
        }
#pragma unroll
    for (int nt = 0; nt < 2; nt++) {
      sw[nt] += __shfl_xor(sw[nt], 16);
      sw[nt] += __shfl_xor(sw[nt], 32);
      if (quad == 0) redS[w][nt * 16 + r16] = sw[nt];
    }
    __syncthreads();
    float inv[2];
#pragma unroll
    for (int nt = 0; nt < 2; nt++) {
      const int q = nt * 16 + r16;
      inv[nt] = 1.f / (redS[0][q] + redS[1][q] + redS[2][q] + redS[3][q]);
    }
#pragma unroll
    for (int nt = 0; nt < 2; nt++) {
      unsigned short* prow = Pl + (nt * 16 + r16) * 264 + w * 64 + quad * 4;
#pragma unroll
      for (int mt = 0; mt < 4; mt++) {
        uint2 u;
        u.x = pack_bf16(acc[mt][nt][0] * inv[nt], acc[mt][nt][1] * inv[nt]);
        u.y = pack_bf16(acc[mt][nt][2] * inv[nt], acc[mt][nt][3] * inv[nt]);
        *(uint2*)(prow + mt * 16) = u;
      }
    }
    __syncthreads();
    f32x4 o[2] = {};
#pragma unroll
    for (int s = 0; s < 8; s++) {
      const bf16x8 aV = *(const bf16x8*)(Vt + (w * 16 + r16) * 264 + s * 32 + quad * 8);
#pragma unroll
      for (int nt = 0; nt < 2; nt++) {
        const bf16x8 bP = *(const bf16x8*)(Pl + (nt * 16 + r16) * 264 + s * 32 + quad * 8);
        o[nt] = __builtin_amdgcn_mfma_f32_16x16x32_bf16(aV, bP, o[nt], 0, 0, 0);
      }
    }
#pragma unroll
    for (int nt = 0; nt < 2; nt++) {
      uint2 u;
      u.x = pack_bf16(o[nt][0], o[nt][1]);
      u.y = pack_bf16(o[nt][2], o[nt][3]);
      *(uint2*)(O + (size_t)(b * 256 + q0 + nt * 16 + r16) * 512 + h * 64 +
                w * 16 + quad * 4) = u;
    }
  }
}

// =====================================================================
// latent: mem[64,256] += xb[64,131072](bf16) . W[256,131072]^T
// bf16 MFMA streaming, W converted fp32->bf16 in-flight, split-K atomics.
// =====================================================================
__global__ void zero_kernel(float* __restrict__ p) {
  p[blockIdx.x * 256 + threadIdx.x] = 0.f;
}

__global__ __launch_bounds__(256) void latent_gemm(
    const unsigned short* __restrict__ xb, const float* __restrict__ W,
    float* __restrict__ mem) {
  const int tid = threadIdx.x;
  const int lane = tid & 63;
  const int w = tid >> 6;
  const int r16 = lane & 15;
  const int quad = lane >> 4;
  const int n0 = blockIdx.x * 64 + w * 16;     // wave's 16 n-rows
  const int kc0 = blockIdx.y * 1024;

  const float* wrow = W + (size_t)(n0 + r16) * 131072 + kc0 + quad * 8;
  const unsigned short* xrow = xb + (size_t)r16 * 131072 + kc0 + quad * 8;

  f32x4 c[4] = {};  // C[b = i*16+quad*4+reg][n = n0+r16]
  for (int k = 0; k < 1024; k += 32) {
    const float4 wa = *(const float4*)(wrow + k);
    const float4 wb = *(const float4*)(wrow + k + 4);
    union { unsigned u[4]; bf16x8 v; } cw;
    cw.u[0] = pack_bf16(wa.x, wa.y);
    cw.u[1] = pack_bf16(wa.z, wa.w);
    cw.u[2] = pack_bf16(wb.x, wb.y);
    cw.u[3] = pack_bf16(wb.z, wb.w);
#pragma unroll
    for (int i = 0; i < 4; i++) {
      const bf16x8 aX = *(const bf16x8*)(xrow + (size_t)i * 2097152 + k);
      c[i] = __builtin_amdgcn_mfma_f32_16x16x32_bf16(aX, cw.v, c[i], 0, 0, 0);
    }
  }
#pragma unroll
  for (int i = 0; i < 4; i++)
#pragma unroll
    for (int r = 0; r < 4; r++)
      atomicAdd(&mem[(size_t)(i * 16 + quad * 4 + r) * 256 + n0 + r16], c[i][r]);
}

// =====================================================================
__global__ __launch_bounds__(256) void head_kernel(
    const float* __restrict__ mem, const float* __restrict__ lat_b,
    const float* __restrict__ head_w, const float* __restrict__ head_b,
    float* __restrict__ out) {
  const int b = blockIdx.x;
  const int tid = threadIdx.x;
  float v = (mem[(size_t)b * 256 + tid] + lat_b[tid]) * head_w[tid];
#pragma unroll
  for (int off = 32; off > 0; off >>= 1) v += __shfl_xor(v, off);
  __shared__ float red[4];
  const int w = tid >> 6, lane = tid & 63;
  if (lane == 0) red[w] = v;
  __syncthreads();
  if (tid == 0) {
    const float z = red[0] + red[1] + red[2] + red[3] + head_b[0];
    out[b] = 1.f / (1.f + __expf(-z));
  }
}

// =====================================================================
extern "C" void kernel_launch(void* const* d_in, const int* in_sizes, int n_in,
                              void* d_out, int out_size, void* d_ws, size_t ws_size,
                              hipStream_t stream) {
  (void)in_sizes; (void)n_in; (void)out_size; (void)ws_size;
  const float* src_pad = (const float*)d_in[0];
  const float* emb_w = (const float*)d_in[1];
  const float* emb_b = (const float*)d_in[2];
  const float* qkv_w = (const float*)d_in[3];
  const float* qkv_b = (const float*)d_in[4];
  const float* out_w = (const float*)d_in[5];
  const float* out_b = (const float*)d_in[6];
  const float* ff1_w = (const float*)d_in[7];
  const float* ff1_b = (const float*)d_in[8];
  const float* ff2_w = (const float*)d_in[9];
  const float* ff2_b = (const float*)d_in[10];
  const float* ln1_g = (const float*)d_in[11];
  const float* ln1_b = (const float*)d_in[12];
  const float* ln2_g = (const float*)d_in[13];
  const float* ln2_b = (const float*)d_in[14];
  const float* lat_w = (const float*)d_in[15];
  const float* lat_b = (const float*)d_in[16];
  const float* head_w = (const float*)d_in[17];
  const float* head_b = (const float*)d_in[18];
  float* out = (float*)d_out;

  // workspace layout (~213 MB)
  char* p = (char*)d_ws;
  float* x = (float*)p;             p += (size_t)16384 * 512 * 4;   // fp32 master
  unsigned short* xb = (unsigned short*)p; p += (size_t)16384 * 512 * 2;  // bf16 of x
  unsigned short* qkv = (unsigned short*)p; p += (size_t)16384 * 1536 * 2;
  unsigned short* attno = (unsigned short*)p; p += (size_t)16384 * 512 * 2;
  unsigned short* h = (unsigned short*)p;     p += (size_t)16384 * 2048 * 2;
  unsigned short* wq = (unsigned short*)p;    p += (size_t)4718592 * 2;
  unsigned short* wo = (unsigned short*)p;    p += (size_t)1572864 * 2;
  unsigned short* wf1 = (unsigned short*)p;   p += (size_t)6291456 * 2;
  unsigned short* wf2 = (unsigned short*)p;   p += (size_t)6291456 * 2;
  float* mem = (float*)p;           p += (size_t)16384 * 4;

  cvt4_kernel<<<4608, 256, 0, stream>>>(qkv_w, wq);
  cvt4_kernel<<<1536, 256, 0, stream>>>(out_w, wo);
  cvt4_kernel<<<6144, 256, 0, stream>>>(ff1_w, wf1);
  cvt4_kernel<<<6144, 256, 0, stream>>>(ff2_w, wf2);

  embed_kernel<<<16384, 512, 0, stream>>>(src_pad, emb_w, emb_b, x, xb);

  for (int l = 0; l < 6; l++) {
    gemm_nt<0><<<dim3(128, 12), 256, 0, stream>>>(
        xb, wq + (size_t)l * 786432, qkv_b + (size_t)l * 1536,
        qkv, 16384, 1536, 512);
    attn_fused<<<512, 256, 0, stream>>>(qkv, attno);
    gemm_ln<<<512, 256, 0, stream>>>(
        attno, wo + (size_t)l * 262144, out_b + (size_t)l * 512,
        ln1_g + (size_t)l * 512, ln1_b + (size_t)l * 512, x, xb, 512);
    gemm_nt<1><<<dim3(128, 16), 256, 0, stream>>>(
        xb, wf1 + (size_t)l * 1048576, ff1_b + (size_t)l * 2048,
        h, 16384, 2048, 512);
    gemm_ln<<<512, 256, 0, stream>>>(
        h, wf2 + (size_t)l * 1048576, ff2_b + (size_t)l * 512,
        ln2_g + (size_t)l * 512, ln2_b + (size_t)l * 512, x, xb, 2048);
  }

  zero_kernel<<<64, 256, 0, stream>>>(mem);
  latent_gemm<<<dim3(4, 128), 256, 0, stream>>>(xb, lat_w, mem);
  head_kernel<<<64, 256, 0, stream>>>(mem, lat_b, head_w, head_b, out);
}

// Round 9
// 1607.024 us; speedup vs baseline: 1.1804x; 1.1804x over previous
//
#include <hip/hip_runtime.h>
#include <hip/hip_bf16.h>
#include <cstdint>

#define DEV static __device__ __forceinline__

typedef __attribute__((ext_vector_type(8))) short bf16x8;
typedef __attribute__((ext_vector_type(4))) float f32x4;

// ---------- bf16 helpers (bit-level) ----------
DEV unsigned short f2bf(float f) {
  union { float f; unsigned u; } c; c.f = f;
  unsigned u = c.u;
  return (unsigned short)((u + 0x7fffu + ((u >> 16) & 1u)) >> 16);  // RNE
}
DEV float bf2f(unsigned short h) {
  union { unsigned u; float f; } c; c.u = ((unsigned)h) << 16; return c.f;
}
DEV float bflo(unsigned u) { union { unsigned u; float f; } c; c.u = u << 16; return c.f; }
DEV float bfhi(unsigned u) { union { unsigned u; float f; } c; c.u = u & 0xffff0000u; return c.f; }
// fast round-half-up bf16 pair pack: lo16 = bf(a), hi16 = bf(b), 3 VALU ops
DEV unsigned pack_bf16(float a, float b) {
  union { float f; unsigned u; } ca, cb; ca.f = a; cb.f = b;
  return __builtin_amdgcn_perm(cb.u + 0x8000u, ca.u + 0x8000u, 0x07060302u);
}

// async global->LDS, 16B per lane; LDS dest is wave-uniform base + lane*16
#define ASYNC_COPY16(gsrc, ldst)                                                      \
  __builtin_amdgcn_global_load_lds(                                                   \
      (const __attribute__((address_space(1))) void*)(unsigned long long)(gsrc),      \
      (__attribute__((address_space(3))) void*)(unsigned int)(unsigned long long)(ldst), \
      16, 0, 0)

// =====================================================================
// fp32 -> bf16 weight conversion, 4 elems/thread
// =====================================================================
__global__ void cvt4_kernel(const float* __restrict__ s, unsigned short* __restrict__ d) {
  size_t i = ((size_t)blockIdx.x * 256 + threadIdx.x) * 4;
  float4 v = *(const float4*)(s + i);
  d[i + 0] = f2bf(v.x);
  d[i + 1] = f2bf(v.y);
  d[i + 2] = f2bf(v.z);
  d[i + 3] = f2bf(v.w);
}

// =====================================================================
// embedding + positional encoding -> xb bf16 (residual stream is bf16)
// =====================================================================
__global__ void embed_kernel(const float* __restrict__ src,    // [B*S,16]
                             const float* __restrict__ emb_w,  // [512,16]
                             const float* __restrict__ emb_b,  // [512]
                             unsigned short* __restrict__ xb) {
  const int bs = blockIdx.x;        // 0..16383
  const int d = threadIdx.x;        // 0..511
  const int s = bs & 255;
  __shared__ float sv[16];
  if (d < 16) sv[d] = src[(size_t)bs * 16 + d];
  __syncthreads();
  const float* wr = emb_w + (size_t)d * 16;
  float acc = emb_b[d];
#pragma unroll
  for (int v = 0; v < 16; v++) acc += sv[v] * wr[v];
  const float den = __expf(-(float)(d & ~1) * (9.2103403719761836f / 512.f));
  const float arg = (float)s * den;
  acc += (d & 1) ? __cosf(arg) : __sinf(arg);
  xb[(size_t)bs * 512 + d] = f2bf(acc);
}

// =====================================================================
// bf16 MFMA GEMM, NT: C[m,n] = sum_k A[m,k]*B[n,k] + bias[n] (+res[m,n])
// BM=128, BN template {128,64}, BK=64, 256 thr.
// Grid: x = m-tiles (XCD = id%8 = m%8 -> A-tile L2 locality), y = n-blocks.
// LDS XOR swizzle (row stride 128B): chunk slot s of row r holds global
// chunk s^(r&7); readers use (kh*4+quad)^(r16&7) -> conflict-free b128.
// Operands swapped (A_op=weights) so lane's 4 acc regs = 4 consecutive n.
// res (if ADD_RES) is the bf16 residual stream.
// =====================================================================
template <int BN, int MINW, int RELU, int OUT_BF16, int ADD_RES>
__global__ __launch_bounds__(256, MINW) void gemm_nt(
    const unsigned short* __restrict__ A,   // [M,K] bf16 activations
    const unsigned short* __restrict__ B,   // [N,K] bf16 weights
    const float* __restrict__ bias,         // [N]
    const unsigned short* __restrict__ res, // [M,N] bf16 residual (if ADD_RES)
    float* __restrict__ Cf,                 // [M,N] if !OUT_BF16
    unsigned short* __restrict__ Cb,        // [M,N] if OUT_BF16
    int M, int N, int K) {
  constexpr int MT = (BN == 128) ? 4 : 2;  // m-tiles/wave
  constexpr int NT = 4;                    // n-tiles/wave
  __shared__ unsigned short As[128 * 64];
  __shared__ unsigned short Bs[BN * 64];
  const int tid = threadIdx.x;
  const int lane = tid & 63;
  const int w = tid >> 6;
  const int m0 = blockIdx.x * 128;   // m fast -> XCD locality for A
  const int n0 = blockIdx.y * BN;

  const int srow = lane >> 3;                  // 0..7
  const int scol = (((lane & 7) ^ srow)) * 8;  // swizzled chunk
  const unsigned short* gA0 = A + (size_t)(m0 + w * 32 + srow) * K + scol;
  unsigned short* lA0 = As + (w * 32) * 64;
  constexpr int BROWS = BN / 4 / 8;  // B-insts per wave: 4 (BN=128) or 2 (BN=64)
  const unsigned short* gB0 = B + (size_t)(n0 + w * (BN / 4) + srow) * K + scol;
  unsigned short* lB0 = Bs + (w * (BN / 4)) * 64;

  const int wm = (BN == 128) ? (w >> 1) * 64 : w * 32;
  const int wn = (BN == 128) ? (w & 1) * 64 : 0;
  const int r16 = lane & 15;
  const int quad = lane >> 4;
  const int rsw = r16 & 7;

  f32x4 acc[MT][NT] = {};  // acc[i][j]: D[n=quad*4+r][m=r16]

  for (int k0 = 0; k0 < K; k0 += 64) {
#pragma unroll
    for (int i = 0; i < 4; i++)
      ASYNC_COPY16(gA0 + (size_t)(i * 8) * K + k0, lA0 + i * 512);
#pragma unroll
    for (int i = 0; i < BROWS; i++)
      ASYNC_COPY16(gB0 + (size_t)(i * 8) * K + k0, lB0 + i * 512);
    __syncthreads();
#pragma unroll
    for (int kh = 0; kh < 2; kh++) {
      const int ko = ((kh * 4 + quad) ^ rsw) * 8;
      bf16x8 xa[MT], wb[NT];
#pragma unroll
      for (int i = 0; i < MT; i++)
        xa[i] = *(const bf16x8*)(As + (wm + i * 16 + r16) * 64 + ko);
#pragma unroll
      for (int j = 0; j < NT; j++)
        wb[j] = *(const bf16x8*)(Bs + (wn + j * 16 + r16) * 64 + ko);
#pragma unroll
      for (int i = 0; i < MT; i++)
#pragma unroll
        for (int j = 0; j < NT; j++)
          acc[i][j] = __builtin_amdgcn_mfma_f32_16x16x32_bf16(wb[j], xa[i], acc[i][j], 0, 0, 0);
    }
    __syncthreads();
  }

  // epilogue: m = m0+wm+i*16+r16, n = n0+wn+j*16+quad*4 (+0..3)
  const int mb = m0 + wm + r16;
  const int nb = n0 + wn + quad * 4;
#pragma unroll
  for (int j = 0; j < NT; j++) {
    const int n = nb + j * 16;
    const float4 bv = *(const float4*)(bias + n);
#pragma unroll
    for (int i = 0; i < MT; i++) {
      const size_t off = (size_t)(mb + i * 16) * N + n;
      float4 v;
      v.x = acc[i][j][0] + bv.x;
      v.y = acc[i][j][1] + bv.y;
      v.z = acc[i][j][2] + bv.z;
      v.w = acc[i][j][3] + bv.w;
      if (ADD_RES) {
        const uint2 ru = *(const uint2*)(res + off);
        v.x += bflo(ru.x); v.y += bfhi(ru.x);
        v.z += bflo(ru.y); v.w += bfhi(ru.y);
      }
      if (RELU) {
        v.x = fmaxf(v.x, 0.f); v.y = fmaxf(v.y, 0.f);
        v.z = fmaxf(v.z, 0.f); v.w = fmaxf(v.w, 0.f);
      }
      if (OUT_BF16) {
        uint2 u;
        u.x = pack_bf16(v.x, v.y);
        u.y = pack_bf16(v.z, v.w);
        *(uint2*)(Cb + off) = u;
      } else {
        *(float4*)(Cf + off) = v;
      }
    }
  }
}

// =====================================================================
// Fused attention: one block per (b,h). V^T staged once (33.8KB);
// loop over 8 q-tiles of 32: S^T scores (wave = k-quarter, A=K, B=Q from
// global), two-phase LDS softmax (max then sum), P packed to LDS (16.9KB,
// stride 264 -> 2-way reads), PV as O^T = Vt.P, uint2 packed O stores.
// =====================================================================
__global__ __launch_bounds__(256, 2) void attn_fused(
    const unsigned short* __restrict__ qkv,  // [B*S,1536] bf16 q|k|v
    unsigned short* __restrict__ O) {        // [B*S,512] bf16
  __shared__ unsigned short Vt[64 * 264];  // V^T[d][k], stride 264
  __shared__ unsigned short Pl[32 * 264];  // P[q][k],  stride 264
  __shared__ float redM[4][32];
  __shared__ float redS[4][32];
  const int tid = threadIdx.x;
  const int lane = tid & 63;
  const int w = tid >> 6;
  const int r16 = lane & 15;
  const int quad = lane >> 4;
  const int h = blockIdx.x & 7;
  const int b = blockIdx.x >> 3;

  // stage V^T (verified round-2 pattern)
  {
    const int kp = w * 32 + (lane & 31);
    const int dhalf = lane >> 5;
    const unsigned short* vbase =
        qkv + (size_t)(b * 256 + 2 * kp) * 1536 + 1024 + h * 64;
    unsigned* dst = (unsigned*)Vt;
#pragma unroll
    for (int t = 0; t < 4; t++) {
      const int dc = dhalf + 2 * t;  // d-chunk 0..7
      const uint4 a = *(const uint4*)(vbase + dc * 8);
      const uint4 bb = *(const uint4*)(vbase + 1536 + dc * 8);
      const unsigned* ap = (const unsigned*)&a;
      const unsigned* bp = (const unsigned*)&bb;
#pragma unroll
      for (int i = 0; i < 4; i++) {
        const unsigned lo = ap[i], hi = bp[i];
        dst[(dc * 8 + 2 * i) * 132 + kp] = (lo & 0xffffu) | (hi << 16);
        dst[(dc * 8 + 2 * i + 1) * 132 + kp] = (lo >> 16) | (hi & 0xffff0000u);
      }
    }
  }
  __syncthreads();

  const unsigned short* krow =
      qkv + (size_t)(b * 256 + r16) * 1536 + 512 + h * 64 + quad * 8;
  const unsigned short* qrow =
      qkv + (size_t)(b * 256 + r16) * 1536 + h * 64 + quad * 8;

  for (int qt = 0; qt < 8; qt++) {
    const int q0 = qt * 32;
    f32x4 acc[4][2] = {};  // acc[mt][nt]: S^T[k=w*64+mt*16+quad*4+r][q=q0+nt*16+r16]
    bf16x8 bQ0[2], bQ1[2];
#pragma unroll
    for (int nt = 0; nt < 2; nt++) {
      const unsigned short* qp = qrow + (size_t)(q0 + nt * 16) * 1536;
      bQ0[nt] = *(const bf16x8*)(qp);
      bQ1[nt] = *(const bf16x8*)(qp + 32);
    }
#pragma unroll
    for (int mt = 0; mt < 4; mt++) {
      const unsigned short* kp = krow + (size_t)(w * 64 + mt * 16) * 1536;
      const bf16x8 aK0 = *(const bf16x8*)(kp);
      const bf16x8 aK1 = *(const bf16x8*)(kp + 32);
#pragma unroll
      for (int nt = 0; nt < 2; nt++) {
        acc[mt][nt] = __builtin_amdgcn_mfma_f32_16x16x32_bf16(aK0, bQ0[nt], acc[mt][nt], 0, 0, 0);
        acc[mt][nt] = __builtin_amdgcn_mfma_f32_16x16x32_bf16(aK1, bQ1[nt], acc[mt][nt], 0, 0, 0);
      }
    }
#pragma unroll
    for (int nt = 0; nt < 2; nt++) {
      float m = acc[0][nt][0];
#pragma unroll
      for (int mt = 0; mt < 4; mt++)
#pragma unroll
        for (int r = 0; r < 4; r++) m = fmaxf(m, acc[mt][nt][r]);
      m = fmaxf(m, __shfl_xor(m, 16));
      m = fmaxf(m, __shfl_xor(m, 32));
      if (quad == 0) redM[w][nt * 16 + r16] = m;
    }
    __syncthreads();
    float mg[2], sw[2];
#pragma unroll
    for (int nt = 0; nt < 2; nt++) {
      const int q = nt * 16 + r16;
      mg[nt] = fmaxf(fmaxf(redM[0][q], redM[1][q]), fmaxf(redM[2][q], redM[3][q]));
      sw[nt] = 0.f;
    }
#pragma unroll
    for (int mt = 0; mt < 4; mt++)
#pragma unroll
      for (int nt = 0; nt < 2; nt++)
#pragma unroll
        for (int r = 0; r < 4; r++) {
          acc[mt][nt][r] = __expf((acc[mt][nt][r] - mg[nt]) * 0.125f);
          sw[nt] += acc[mt][nt][r];
        }
#pragma unroll
    for (int nt = 0; nt < 2; nt++) {
      sw[nt] += __shfl_xor(sw[nt], 16);
      sw[nt] += __shfl_xor(sw[nt], 32);
      if (quad == 0) redS[w][nt * 16 + r16] = sw[nt];
    }
    __syncthreads();
    float inv[2];
#pragma unroll
    for (int nt = 0; nt < 2; nt++) {
      const int q = nt * 16 + r16;
      inv[nt] = 1.f / (redS[0][q] + redS[1][q] + redS[2][q] + redS[3][q]);
    }
#pragma unroll
    for (int nt = 0; nt < 2; nt++) {
      unsigned short* prow = Pl + (nt * 16 + r16) * 264 + w * 64 + quad * 4;
#pragma unroll
      for (int mt = 0; mt < 4; mt++) {
        uint2 u;
        u.x = pack_bf16(acc[mt][nt][0] * inv[nt], acc[mt][nt][1] * inv[nt]);
        u.y = pack_bf16(acc[mt][nt][2] * inv[nt], acc[mt][nt][3] * inv[nt]);
        *(uint2*)(prow + mt * 16) = u;
      }
    }
    __syncthreads();
    f32x4 o[2] = {};
#pragma unroll
    for (int s = 0; s < 8; s++) {
      const bf16x8 aV = *(const bf16x8*)(Vt + (w * 16 + r16) * 264 + s * 32 + quad * 8);
#pragma unroll
      for (int nt = 0; nt < 2; nt++) {
        const bf16x8 bP = *(const bf16x8*)(Pl + (nt * 16 + r16) * 264 + s * 32 + quad * 8);
        o[nt] = __builtin_amdgcn_mfma_f32_16x16x32_bf16(aV, bP, o[nt], 0, 0, 0);
      }
    }
#pragma unroll
    for (int nt = 0; nt < 2; nt++) {
      uint2 u;
      u.x = pack_bf16(o[nt][0], o[nt][1]);
      u.y = pack_bf16(o[nt][2], o[nt][3]);
      *(uint2*)(O + (size_t)(b * 256 + q0 + nt * 16 + r16) * 512 + h * 64 +
                w * 16 + quad * 4) = u;
    }
  }
}

// =====================================================================
// LayerNorm over z fp32 -> xb bf16 only (residual stream is bf16)
// =====================================================================
__global__ __launch_bounds__(256) void ln_kernel(
    const float* __restrict__ z, const float* __restrict__ g,
    const float* __restrict__ bb, unsigned short* __restrict__ xb) {
  const int row = blockIdx.x;
  const int tid = threadIdx.x;
  const size_t base = (size_t)row * 512;
  float v0 = z[base + tid];
  float v1 = z[base + tid + 256];
  float s = v0 + v1, ss = v0 * v0 + v1 * v1;
#pragma unroll
  for (int off = 32; off > 0; off >>= 1) {
    s += __shfl_xor(s, off);
    ss += __shfl_xor(ss, off);
  }
  __shared__ float red[8];
  const int w = tid >> 6, lane = tid & 63;
  if (lane == 0) { red[w * 2] = s; red[w * 2 + 1] = ss; }
  __syncthreads();
  s = red[0] + red[2] + red[4] + red[6];
  ss = red[1] + red[3] + red[5] + red[7];
  const float mu = s * (1.f / 512.f);
  const float var = ss * (1.f / 512.f) - mu * mu;
  const float rs = rsqrtf(var + 1e-5f);
  const float o0 = (v0 - mu) * rs * g[tid] + bb[tid];
  const float o1 = (v1 - mu) * rs * g[tid + 256] + bb[tid + 256];
  xb[base + tid] = f2bf(o0);
  xb[base + tid + 256] = f2bf(o1);
}

// =====================================================================
// latent: mem[64,256] += xb[64,131072](bf16) . W[256,131072]^T
// bf16 MFMA streaming, W converted fp32->bf16 in-flight, split-K atomics.
// =====================================================================
__global__ void zero_kernel(float* __restrict__ p) {
  p[blockIdx.x * 256 + threadIdx.x] = 0.f;
}

__global__ __launch_bounds__(256) void latent_gemm(
    const unsigned short* __restrict__ xb, const float* __restrict__ W,
    float* __restrict__ mem) {
  const int tid = threadIdx.x;
  const int lane = tid & 63;
  const int w = tid >> 6;
  const int r16 = lane & 15;
  const int quad = lane >> 4;
  const int n0 = blockIdx.x * 64 + w * 16;     // wave's 16 n-rows
  const int kc0 = blockIdx.y * 1024;

  const float* wrow = W + (size_t)(n0 + r16) * 131072 + kc0 + quad * 8;
  const unsigned short* xrow = xb + (size_t)r16 * 131072 + kc0 + quad * 8;

  f32x4 c[4] = {};  // C[b = i*16+quad*4+reg][n = n0+r16]
  for (int k = 0; k < 1024; k += 32) {
    const float4 wa = *(const float4*)(wrow + k);
    const float4 wb = *(const float4*)(wrow + k + 4);
    union { unsigned u[4]; bf16x8 v; } cw;
    cw.u[0] = pack_bf16(wa.x, wa.y);
    cw.u[1] = pack_bf16(wa.z, wa.w);
    cw.u[2] = pack_bf16(wb.x, wb.y);
    cw.u[3] = pack_bf16(wb.z, wb.w);
#pragma unroll
    for (int i = 0; i < 4; i++) {
      const bf16x8 aX = *(const bf16x8*)(xrow + (size_t)i * 2097152 + k);
      c[i] = __builtin_amdgcn_mfma_f32_16x16x32_bf16(aX, cw.v, c[i], 0, 0, 0);
    }
  }
#pragma unroll
  for (int i = 0; i < 4; i++)
#pragma unroll
    for (int r = 0; r < 4; r++)
      atomicAdd(&mem[(size_t)(i * 16 + quad * 4 + r) * 256 + n0 + r16], c[i][r]);
}

// =====================================================================
__global__ __launch_bounds__(256) void head_kernel(
    const float* __restrict__ mem, const float* __restrict__ lat_b,
    const float* __restrict__ head_w, const float* __restrict__ head_b,
    float* __restrict__ out) {
  const int b = blockIdx.x;
  const int tid = threadIdx.x;
  float v = (mem[(size_t)b * 256 + tid] + lat_b[tid]) * head_w[tid];
#pragma unroll
  for (int off = 32; off > 0; off >>= 1) v += __shfl_xor(v, off);
  __shared__ float red[4];
  const int w = tid >> 6, lane = tid & 63;
  if (lane == 0) red[w] = v;
  __syncthreads();
  if (tid == 0) {
    const float z = red[0] + red[1] + red[2] + red[3] + head_b[0];
    out[b] = 1.f / (1.f + __expf(-z));
  }
}

// =====================================================================
extern "C" void kernel_launch(void* const* d_in, const int* in_sizes, int n_in,
                              void* d_out, int out_size, void* d_ws, size_t ws_size,
                              hipStream_t stream) {
  (void)in_sizes; (void)n_in; (void)out_size; (void)ws_size;
  const float* src_pad = (const float*)d_in[0];
  const float* emb_w = (const float*)d_in[1];
  const float* emb_b = (const float*)d_in[2];
  const float* qkv_w = (const float*)d_in[3];
  const float* qkv_b = (const float*)d_in[4];
  const float* out_w = (const float*)d_in[5];
  const float* out_b = (const float*)d_in[6];
  const float* ff1_w = (const float*)d_in[7];
  const float* ff1_b = (const float*)d_in[8];
  const float* ff2_w = (const float*)d_in[9];
  const float* ff2_b = (const float*)d_in[10];
  const float* ln1_g = (const float*)d_in[11];
  const float* ln1_b = (const float*)d_in[12];
  const float* ln2_g = (const float*)d_in[13];
  const float* ln2_b = (const float*)d_in[14];
  const float* lat_w = (const float*)d_in[15];
  const float* lat_b = (const float*)d_in[16];
  const float* head_w = (const float*)d_in[17];
  const float* head_b = (const float*)d_in[18];
  float* out = (float*)d_out;

  // workspace layout (~180 MB)
  char* p = (char*)d_ws;
  unsigned short* xb = (unsigned short*)p; p += (size_t)16384 * 512 * 2;  // bf16 residual stream
  unsigned short* qkv = (unsigned short*)p;                         // [16384,1536] bf16
  float* y = (float*)qkv;           // fp32 [16384,512] aliases qkv (disjoint lifetimes)
  p += (size_t)16384 * 1536 * 2;
  unsigned short* attno = (unsigned short*)p; p += (size_t)16384 * 512 * 2;
  unsigned short* h = (unsigned short*)p;     p += (size_t)16384 * 2048 * 2;
  unsigned short* wq = (unsigned short*)p;    p += (size_t)4718592 * 2;
  unsigned short* wo = (unsigned short*)p;    p += (size_t)1572864 * 2;
  unsigned short* wf1 = (unsigned short*)p;   p += (size_t)6291456 * 2;
  unsigned short* wf2 = (unsigned short*)p;   p += (size_t)6291456 * 2;
  float* mem = (float*)p;           p += (size_t)16384 * 4;

  cvt4_kernel<<<4608, 256, 0, stream>>>(qkv_w, wq);
  cvt4_kernel<<<1536, 256, 0, stream>>>(out_w, wo);
  cvt4_kernel<<<6144, 256, 0, stream>>>(ff1_w, wf1);
  cvt4_kernel<<<6144, 256, 0, stream>>>(ff2_w, wf2);

  embed_kernel<<<16384, 512, 0, stream>>>(src_pad, emb_w, emb_b, xb);

  for (int l = 0; l < 6; l++) {
    gemm_nt<128, 3, 0, 1, 0><<<dim3(128, 12), 256, 0, stream>>>(
        xb, wq + (size_t)l * 786432, qkv_b + (size_t)l * 1536, nullptr,
        nullptr, qkv, 16384, 1536, 512);
    attn_fused<<<512, 256, 0, stream>>>(qkv, attno);
    gemm_nt<64, 4, 0, 0, 1><<<dim3(128, 8), 256, 0, stream>>>(
        attno, wo + (size_t)l * 262144, out_b + (size_t)l * 512, xb,
        y, nullptr, 16384, 512, 512);
    ln_kernel<<<16384, 256, 0, stream>>>(y, ln1_g + (size_t)l * 512,
                                         ln1_b + (size_t)l * 512, xb);
    gemm_nt<128, 3, 1, 1, 0><<<dim3(128, 16), 256, 0, stream>>>(
        xb, wf1 + (size_t)l * 1048576, ff1_b + (size_t)l * 2048, nullptr,
        nullptr, h, 16384, 2048, 512);
    gemm_nt<64, 4, 0, 0, 1><<<dim3(128, 8), 256, 0, stream>>>(
        h, wf2 + (size_t)l * 1048576, ff2_b + (size_t)l * 512, xb,
        y, nullptr, 16384, 512, 2048);
    ln_kernel<<<16384, 256, 0, stream>>>(y, ln2_g + (size_t)l * 512,
                                         ln2_b + (size_t)l * 512, xb);
  }

  zero_kernel<<<64, 256, 0, stream>>>(mem);
  latent_gemm<<<dim3(4, 128), 256, 0, stream>>>(xb, lat_w, mem);
  head_kernel<<<64, 256, 0, stream>>>(mem, lat_b, head_w, head_b, out);
}